// Round 1
// 298.569 us; speedup vs baseline: 1.0979x; 1.0979x over previous
//
#include <hip/hip_runtime.h>
#include <hip/hip_bf16.h>
#include <stdint.h>

typedef __bf16 bf16x8 __attribute__((ext_vector_type(8)));
typedef float  f32x4  __attribute__((ext_vector_type(4)));

#define M_NODES 100000
#define K_IN    256
#define N_OUT   128
#define N_EDGE  1600000

// ---------------------------------------------------------------------------
// Stage 1: h[M,N] = in[M,K] @ w[K,N]. fp32 loads -> bf16 cvt -> MFMA
// 16x16x32 (fp32 accum). Writes fp32 h (nontemporal; never re-read) to d_out
// and a bf16 mirror (cached; stage 2 gathers it) to d_ws.
//
// v2: the wave's entire B panel (its 32 cols x all 256 k, bf16) is preloaded
// into 64 VGPRs ONCE per block; blocks grid-stride over row tiles (grid=512
// = 2 blocks/CU at ~2 waves/SIMD, ~3 tiles/block) so the per-k-step 16 scalar
// w loads + 16 cvts disappear from the inner loop. Boundary tile takes a
// separate guarded path so the hot path is guard-free.
// Fragment layouts verified in prior session (R2 MFMA == R4 VALU bytes).
// ---------------------------------------------------------------------------
template <bool FULL>
__device__ __forceinline__ void gemm_tile(
    const float* __restrict__ in, float* __restrict__ h,
    __hip_bfloat16* __restrict__ hmir,
    const bf16x8 (&bfrag)[8][2], const int m0, const int lr, const int q,
    const int nb)
{
    f32x4 acc[4][2];
    #pragma unroll
    for (int mt = 0; mt < 4; ++mt)
        #pragma unroll
        for (int nt = 0; nt < 2; ++nt)
            acc[mt][nt] = f32x4{0.f, 0.f, 0.f, 0.f};

    #pragma unroll
    for (int k8 = 0; k8 < 8; ++k8) {
        const int ka = k8 * 32 + q * 8;      // lane's 8 contiguous k
        bf16x8 afrag[4];                     // A[m=lr][k=ka..ka+7]
        #pragma unroll
        for (int mt = 0; mt < 4; ++mt) {
            const int row = m0 + mt * 16 + lr;
            if (FULL || row < M_NODES) {
                const float* ap = in + (size_t)row * K_IN + ka;
                const f32x4 a0 = *(const f32x4*)ap;
                const f32x4 a1 = *(const f32x4*)(ap + 4);
                #pragma unroll
                for (int j = 0; j < 4; ++j) {
                    afrag[mt][j]     = (__bf16)a0[j];
                    afrag[mt][4 + j] = (__bf16)a1[j];
                }
            } else {
                #pragma unroll
                for (int j = 0; j < 8; ++j) afrag[mt][j] = (__bf16)0.f;
            }
        }
        #pragma unroll
        for (int mt = 0; mt < 4; ++mt)
            #pragma unroll
            for (int nt = 0; nt < 2; ++nt)
                acc[mt][nt] = __builtin_amdgcn_mfma_f32_16x16x32_bf16(
                    afrag[mt], bfrag[k8][nt], acc[mt][nt], 0, 0, 0);
    }

    // C/D: col = lane&15, row = (lane>>4)*4 + reg
    #pragma unroll
    for (int mt = 0; mt < 4; ++mt) {
        const int rb = m0 + mt * 16 + q * 4;
        if (!FULL && rb >= M_NODES) continue; // M%4==0: rb<M => rb+3<M
        #pragma unroll
        for (int nt = 0; nt < 2; ++nt) {
            const int col = nb + nt * 16 + lr;
            #pragma unroll
            for (int r = 0; r < 4; ++r) {
                const float v = acc[mt][nt][r];
                __builtin_nontemporal_store(v, h + (size_t)(rb + r) * N_OUT + col);
                hmir[(size_t)(rb + r) * N_OUT + col] = __float2bfloat16(v);
            }
        }
    }
}

__global__ __launch_bounds__(256) void gemm_h_mfma(
    const float* __restrict__ in,            // [M,K] fp32
    const float* __restrict__ w,             // [K,N] fp32
    float* __restrict__ h,                   // [M,N] fp32 (d_out)
    __hip_bfloat16* __restrict__ hmir)       // [M,N] bf16 mirror (d_ws)
{
    const int lane = threadIdx.x & 63;
    const int wave = threadIdx.x >> 6;       // 0..3
    const int nb   = wave * 32;
    const int lr   = lane & 15;              // m (A) / n (B,C) within tile
    const int q    = lane >> 4;              // quad 0..3

    // Preload the wave's full B panel: bfrag[k8][nt][j] = w[k8*32+q*8+j][nb+nt*16+lr]
    bf16x8 bfrag[8][2];
    #pragma unroll
    for (int k8 = 0; k8 < 8; ++k8) {
        const int ka = k8 * 32 + q * 8;
        #pragma unroll
        for (int nt = 0; nt < 2; ++nt) {
            const int col = nb + nt * 16 + lr;
            #pragma unroll
            for (int j = 0; j < 8; ++j)
                bfrag[k8][nt][j] = (__bf16)w[(size_t)(ka + j) * N_OUT + col];
        }
    }

    const int ntiles = (M_NODES + 63) / 64;  // 1563
    const int nfull  = M_NODES / 64;         // 1562 guard-free tiles
    for (int t = blockIdx.x; t < ntiles; t += gridDim.x) {
        const int m0 = t * 64;
        if (t < nfull) gemm_tile<true >(in, h, hmir, bfrag, m0, lr, q, nb);
        else           gemm_tile<false>(in, h, hmir, bfrag, m0, lr, q, nb);
    }
}

// int64 edge indices < 1e5: every high word is 0. int32: odd words random.
__device__ inline int detect_i64(const uint32_t* p) {
    return __popcll(__ballot(p[2 * (threadIdx.x & 63) + 1] == 0u)) >= 60;
}

// ---------------------------------------------------------------------------
// Stage 2: edge_weight[e] = relu( sum_k |h[src][k] - h[dst][k]| * a[k] ).
// 16 lanes per edge; lane covers 8 contiguous channels (16B bf16 loads).
//
// v2: each 16-lane group handles 4 CONSECUTIVE edges — index loads become
// two uint4 vector loads, the output becomes one f32x4 store, `a` is loaded
// once, and each lane has 8 independent 16B gathers in flight (4x the MLP).
// ---------------------------------------------------------------------------
__global__ __launch_bounds__(256) void edge_kernel_bf16(
    const __hip_bfloat16* __restrict__ hm,   // [M,N] bf16 mirror
    const uint32_t* __restrict__ edge_raw,   // [2,E] int64 or int32
    const float* __restrict__ a,             // [N] fp32
    float* __restrict__ ew,                  // [E] fp32 out
    int E)
{
    const int e64 = detect_i64(edge_raw);    // before any divergence/return
    const int s  = threadIdx.x & 15;
    const int g  = (int)((blockIdx.x * 256 + threadIdx.x) >> 4);
    const int e0 = g * 4;
    if (e0 >= E) return;

    const __bf16* hb = (const __bf16*)hm;
    const f32x4 a0 = *(const f32x4*)(a + s * 8);
    const f32x4 a1 = *(const f32x4*)(a + s * 8 + 4);

    if (e0 + 3 < E) {
        int srcs[4], dsts[4];
        if (e64) {
            const uint4 s01 = *(const uint4*)(edge_raw + 2 * (size_t)e0);
            const uint4 s23 = *(const uint4*)(edge_raw + 2 * (size_t)e0 + 4);
            const uint4 d01 = *(const uint4*)(edge_raw + 2 * ((size_t)E + e0));
            const uint4 d23 = *(const uint4*)(edge_raw + 2 * ((size_t)E + e0) + 4);
            srcs[0] = (int)s01.x; srcs[1] = (int)s01.z;
            srcs[2] = (int)s23.x; srcs[3] = (int)s23.z;
            dsts[0] = (int)d01.x; dsts[1] = (int)d01.z;
            dsts[2] = (int)d23.x; dsts[3] = (int)d23.z;
        } else {
            const int4 sv = *(const int4*)((const int*)edge_raw + e0);
            const int4 dv = *(const int4*)((const int*)edge_raw + (size_t)E + e0);
            srcs[0] = sv.x; srcs[1] = sv.y; srcs[2] = sv.z; srcs[3] = sv.w;
            dsts[0] = dv.x; dsts[1] = dv.y; dsts[2] = dv.z; dsts[3] = dv.w;
        }

        bf16x8 hs[4], hd[4];                 // 8 independent gathers in flight
        #pragma unroll
        for (int u = 0; u < 4; ++u) {
            hs[u] = *(const bf16x8*)(hb + (size_t)srcs[u] * N_OUT + s * 8);
            hd[u] = *(const bf16x8*)(hb + (size_t)dsts[u] * N_OUT + s * 8);
        }

        f32x4 r;
        #pragma unroll
        for (int u = 0; u < 4; ++u) {
            float sum = 0.f;
            #pragma unroll
            for (int i = 0; i < 4; ++i)
                sum += fabsf((float)hs[u][i] - (float)hd[u][i]) * a0[i];
            #pragma unroll
            for (int i = 0; i < 4; ++i)
                sum += fabsf((float)hs[u][4 + i] - (float)hd[u][4 + i]) * a1[i];
            sum += __shfl_xor(sum, 1, 64);
            sum += __shfl_xor(sum, 2, 64);
            sum += __shfl_xor(sum, 4, 64);
            sum += __shfl_xor(sum, 8, 64);
            r[u] = fmaxf(sum, 0.f);
        }
        if (s == 0) *(f32x4*)(ew + e0) = r;
    } else {
        // tail (E not a multiple of 4): per-edge scalar path
        for (int e = e0; e < E; ++e) {
            int src, dst;
            if (e64) {
                src = (int)edge_raw[2 * (size_t)e];
                dst = (int)edge_raw[2 * ((size_t)E + e)];
            } else {
                const int* e32 = (const int*)edge_raw;
                src = e32[e];
                dst = e32[(size_t)E + e];
            }
            const bf16x8 hs = *(const bf16x8*)(hb + (size_t)src * N_OUT + s * 8);
            const bf16x8 hd = *(const bf16x8*)(hb + (size_t)dst * N_OUT + s * 8);
            float sum = 0.f;
            #pragma unroll
            for (int i = 0; i < 4; ++i)
                sum += fabsf((float)hs[i] - (float)hd[i]) * a0[i];
            #pragma unroll
            for (int i = 0; i < 4; ++i)
                sum += fabsf((float)hs[4 + i] - (float)hd[4 + i]) * a1[i];
            sum += __shfl_xor(sum, 1, 64);
            sum += __shfl_xor(sum, 2, 64);
            sum += __shfl_xor(sum, 4, 64);
            sum += __shfl_xor(sum, 8, 64);
            if (s == 0) ew[e] = fmaxf(sum, 0.f);
        }
    }
}

// fp32 fallback when d_ws can't hold the mirror.
__global__ __launch_bounds__(256) void edge_kernel_f32(
    const float* __restrict__ h,
    const uint32_t* __restrict__ edge_raw,
    const float* __restrict__ a,
    float* __restrict__ ew,
    int E)
{
    const int e64 = detect_i64(edge_raw);
    const int s = threadIdx.x & 15;
    const int e = (int)((blockIdx.x * 256 + threadIdx.x) >> 4);
    if (e >= E) return;

    int src, dst;
    if (e64) {
        src = (int)edge_raw[2 * (size_t)e];
        dst = (int)edge_raw[2 * ((size_t)E + e)];
    } else {
        const int* e32 = (const int*)edge_raw;
        src = e32[e];
        dst = e32[(size_t)E + e];
    }

    const f32x4 s0 = *(const f32x4*)(h + (size_t)src * N_OUT + s * 8);
    const f32x4 s1 = *(const f32x4*)(h + (size_t)src * N_OUT + s * 8 + 4);
    const f32x4 d0 = *(const f32x4*)(h + (size_t)dst * N_OUT + s * 8);
    const f32x4 d1 = *(const f32x4*)(h + (size_t)dst * N_OUT + s * 8 + 4);
    const f32x4 a0 = *(const f32x4*)(a + s * 8);
    const f32x4 a1 = *(const f32x4*)(a + s * 8 + 4);

    float sum = 0.f;
    #pragma unroll
    for (int i = 0; i < 4; ++i) sum += fabsf(s0[i] - d0[i]) * a0[i];
    #pragma unroll
    for (int i = 0; i < 4; ++i) sum += fabsf(s1[i] - d1[i]) * a1[i];

    sum += __shfl_xor(sum, 1, 64);
    sum += __shfl_xor(sum, 2, 64);
    sum += __shfl_xor(sum, 4, 64);
    sum += __shfl_xor(sum, 8, 64);

    if (s == 0) ew[e] = fmaxf(sum, 0.f);
}

extern "C" void kernel_launch(void* const* d_in, const int* in_sizes, int n_in,
                              void* d_out, int out_size, void* d_ws, size_t ws_size,
                              hipStream_t stream) {
    // d_in = { inputs fp32[100000,256], edge int64[2,E], weight fp32[256,128],
    //          a fp32[128,1] }   (documented dict order — validated R0-R6)
    // d_out = fp32: h[100000,128] then edge_weight[E].
    const float*    in   = (const float*)d_in[0];
    const uint32_t* edge = (const uint32_t*)d_in[1];
    const float*    w    = (const float*)d_in[2];
    const float*    a    = (const float*)d_in[3];

    float* h  = (float*)d_out;
    float* ew = h + (size_t)M_NODES * N_OUT;

    const size_t mirror_bytes = (size_t)M_NODES * N_OUT * sizeof(__hip_bfloat16);
    __hip_bfloat16* hmir =
        (ws_size >= mirror_bytes) ? (__hip_bfloat16*)d_ws : nullptr;

    // grid=512: exactly 2 blocks/CU at 2 waves/SIMD; ~3 row-tiles per block
    // amortize the per-block B-panel preload.
    if (hmir) {
        gemm_h_mfma<<<dim3(512), dim3(256), 0, stream>>>(in, w, h, hmir);
        const int egroups = (N_EDGE + 3) / 4;            // 4 edges / 16 lanes
        const int eblocks = (egroups * 16 + 255) / 256;  // 25000
        edge_kernel_bf16<<<dim3(eblocks), dim3(256), 0, stream>>>(
            hmir, edge, a, ew, N_EDGE);
    } else {
        gemm_h_mfma<<<dim3(512), dim3(256), 0, stream>>>(
            in, w, h, (__hip_bfloat16*)d_ws);  // unreachable in practice
        const int eblocks = (N_EDGE * 16 + 255) / 256;
        edge_kernel_f32<<<dim3(eblocks), dim3(256), 0, stream>>>(
            h, edge, a, ew, N_EDGE);
    }
}